// Round 1
// baseline (86.811 us; speedup 1.0000x reference)
//
#include <hip/hip_runtime.h>

#define RADIUS 5
#define KSIZE  11           // 2*RADIUS+1
#define TILE   16
#define HALO   (TILE + 2*RADIUS)   // 26
#define PITCH  (HALO + 1)          // 27 — breaks pow2 bank stride
#define H      256
#define W      256

// sigma_inv = 1/SIGMA_DIAG = {0.1,0.1,50,50,50,10,10,10}
// coef[c]   = -0.5 * log2(e) * sigma_inv[c]   (fold exp->exp2 conversion in)
__constant__ float kCoef[8] = {
    -0.072134752f, -0.072134752f,
    -36.06737602f, -36.06737602f, -36.06737602f,
    -7.213475204f, -7.213475204f, -7.213475204f
};

__global__ __launch_bounds__(256) void jbf_kernel(
    const float* __restrict__ image,     // (B,3,H,W)
    const float* __restrict__ guidance,  // (B,8,H,W)
    float* __restrict__ out)             // (B,3,H,W)
{
    __shared__ float g_s[8][HALO][PITCH];
    __shared__ float i_s[3][HALO][PITCH];

    const int b       = blockIdx.z;
    const int tile_x0 = blockIdx.x * TILE;
    const int tile_y0 = blockIdx.y * TILE;
    const int tid     = threadIdx.y * TILE + threadIdx.x;

    const float* gbase = guidance + (size_t)b * 8 * H * W;
    const float* ibase = image    + (size_t)b * 3 * H * W;

    // ---- stage halo tile (reflect padding) into LDS ----
    for (int idx = tid; idx < HALO * HALO; idx += TILE * TILE) {
        const int ly = idx / HALO;
        const int lx = idx - ly * HALO;
        int gy = tile_y0 - RADIUS + ly;
        int gx = tile_x0 - RADIUS + lx;
        gy = (gy < 0) ? -gy : ((gy >= H) ? 2 * (H - 1) - gy : gy);
        gx = (gx < 0) ? -gx : ((gx >= W) ? 2 * (W - 1) - gx : gx);
        const int off = gy * W + gx;
        #pragma unroll
        for (int c = 0; c < 8; ++c)
            g_s[c][ly][lx] = gbase[c * (H * W) + off];
        #pragma unroll
        for (int c = 0; c < 3; ++c)
            i_s[c][ly][lx] = ibase[c * (H * W) + off];
    }
    __syncthreads();

    const int tx = threadIdx.x;
    const int ty = threadIdx.y;

    // center guidance vector
    float gc[8];
    #pragma unroll
    for (int c = 0; c < 8; ++c)
        gc[c] = g_s[c][ty + RADIUS][tx + RADIUS];

    float acc0 = 0.f, acc1 = 0.f, acc2 = 0.f, sw = 0.f;

    for (int dy = 0; dy < KSIZE; ++dy) {
        #pragma unroll
        for (int dx = 0; dx < KSIZE; ++dx) {
            float m = 0.f;
            #pragma unroll
            for (int c = 0; c < 8; ++c) {
                const float d = g_s[c][ty + dy][tx + dx] - gc[c];
                m += (kCoef[c] * d) * d;
            }
            const float w = __builtin_amdgcn_exp2f(m);  // v_exp_f32
            sw   += w;
            acc0 += w * i_s[0][ty + dy][tx + dx];
            acc1 += w * i_s[1][ty + dy][tx + dx];
            acc2 += w * i_s[2][ty + dy][tx + dx];
        }
    }

    // sw >= 1 (center weight = exp(0)); reference clip(1e-10) is a no-op
    const float inv = 1.0f / sw;
    const size_t o = (size_t)b * 3 * H * W + (size_t)(tile_y0 + ty) * W
                   + (size_t)(tile_x0 + tx);
    out[o]             = acc0 * inv;
    out[o + H * W]     = acc1 * inv;
    out[o + 2 * H * W] = acc2 * inv;
}

extern "C" void kernel_launch(void* const* d_in, const int* in_sizes, int n_in,
                              void* d_out, int out_size, void* d_ws, size_t ws_size,
                              hipStream_t stream) {
    const float* image    = (const float*)d_in[0];
    const float* guidance = (const float*)d_in[1];
    float* out            = (float*)d_out;

    const int B = in_sizes[0] / (3 * H * W);   // = 2
    dim3 grid(W / TILE, H / TILE, B);
    dim3 block(TILE, TILE);
    hipLaunchKernelGGL(jbf_kernel, grid, block, 0, stream, image, guidance, out);
}

// Round 2
// 77.023 us; speedup vs baseline: 1.1271x; 1.1271x over previous
//
#include <hip/hip_runtime.h>

#define RADIUS 5
#define KSIZE  11                  // 2*RADIUS+1
#define TILE   16
#define HALO   (TILE + 2*RADIUS)   // 26
#define RP     27                  // row pitch in PIXELS (odd -> bank stagger)
#define H      256
#define W      256

// Mahalanobis coefficients folded with -0.5*log2(e) for exp2:
//   sigma_inv groups: ch0-1 = 0.1, ch2-4 = 50, ch5-7 = 10
#define COEF_A (-0.072134752f)     // -0.5*log2e*0.1
#define COEF_B (-36.06737602f)     // -0.5*log2e*50
#define COEF_C (-7.213475204f)     // -0.5*log2e*10

__global__ __launch_bounds__(256) void jbf_kernel(
    const float* __restrict__ image,     // (B,3,H,W)
    const float* __restrict__ guidance,  // (B,8,H,W)
    float* __restrict__ out)             // (B,3,H,W)
{
    // pixel-interleaved float4 planes: one ds_read_b128 = 4 channels of a pixel
    __shared__ float4 g0_s[HALO * RP];   // guidance ch 0..3
    __shared__ float4 g1_s[HALO * RP];   // guidance ch 4..7
    __shared__ float4 im_s[HALO * RP];   // image ch 0..2 (+pad)

    const int b       = blockIdx.z;
    const int tile_x0 = blockIdx.x * TILE;
    const int tile_y0 = blockIdx.y * TILE;
    const int tid     = threadIdx.y * TILE + threadIdx.x;

    const float* gbase = guidance + (size_t)b * 8 * H * W;
    const float* ibase = image    + (size_t)b * 3 * H * W;

    // ---- stage halo tile (reflect padding) into interleaved LDS ----
    for (int idx = tid; idx < HALO * HALO; idx += TILE * TILE) {
        const int ly = idx / HALO;
        const int lx = idx - ly * HALO;
        int gy = tile_y0 - RADIUS + ly;
        int gx = tile_x0 - RADIUS + lx;
        gy = (gy < 0) ? -gy : ((gy >= H) ? 2 * (H - 1) - gy : gy);
        gx = (gx < 0) ? -gx : ((gx >= W) ? 2 * (W - 1) - gx : gx);
        const int off = gy * W + gx;
        const int l   = ly * RP + lx;
        g0_s[l] = make_float4(gbase[0 * H * W + off], gbase[1 * H * W + off],
                              gbase[2 * H * W + off], gbase[3 * H * W + off]);
        g1_s[l] = make_float4(gbase[4 * H * W + off], gbase[5 * H * W + off],
                              gbase[6 * H * W + off], gbase[7 * H * W + off]);
        im_s[l] = make_float4(ibase[0 * H * W + off], ibase[1 * H * W + off],
                              ibase[2 * H * W + off], 0.f);
    }
    __syncthreads();

    const int tx = threadIdx.x;
    const int ty = threadIdx.y;

    const float4 cA = g0_s[(ty + RADIUS) * RP + tx + RADIUS];
    const float4 cB = g1_s[(ty + RADIUS) * RP + tx + RADIUS];

    float acc0 = 0.f, acc1 = 0.f, acc2 = 0.f, sw = 0.f;

    for (int dy = 0; dy < KSIZE; ++dy) {
        const int base = (ty + dy) * RP + tx;
        #pragma unroll
        for (int dx = 0; dx < KSIZE; ++dx) {
            const float4 a = g0_s[base + dx];
            const float4 g = g1_s[base + dx];
            const float4 p = im_s[base + dx];

            const float d0 = a.x - cA.x, d1 = a.y - cA.y;
            const float d2 = a.z - cA.z, d3 = a.w - cA.w;
            const float d4 = g.x - cB.x, d5 = g.y - cB.y;
            const float d6 = g.z - cB.z, d7 = g.w - cB.w;

            const float sA = d0 * d0 + d1 * d1;              // sigma 10
            const float sB = d2 * d2 + d3 * d3 + d4 * d4;    // sigma 0.02
            const float sC = d5 * d5 + d6 * d6 + d7 * d7;    // sigma 0.1

            const float m = COEF_A * sA + COEF_B * sB + COEF_C * sC;
            const float w = __builtin_amdgcn_exp2f(m);       // v_exp_f32

            sw   += w;
            acc0 += w * p.x;
            acc1 += w * p.y;
            acc2 += w * p.z;
        }
    }

    // sw >= 1 (center weight = exp(0)); reference clip(1e-10) is a no-op
    const float inv = 1.0f / sw;
    const size_t o = (size_t)b * 3 * H * W + (size_t)(tile_y0 + ty) * W
                   + (size_t)(tile_x0 + tx);
    out[o]             = acc0 * inv;
    out[o + H * W]     = acc1 * inv;
    out[o + 2 * H * W] = acc2 * inv;
}

extern "C" void kernel_launch(void* const* d_in, const int* in_sizes, int n_in,
                              void* d_out, int out_size, void* d_ws, size_t ws_size,
                              hipStream_t stream) {
    const float* image    = (const float*)d_in[0];
    const float* guidance = (const float*)d_in[1];
    float* out            = (float*)d_out;

    const int B = in_sizes[0] / (3 * H * W);   // = 2
    dim3 grid(W / TILE, H / TILE, B);
    dim3 block(TILE, TILE);
    hipLaunchKernelGGL(jbf_kernel, grid, block, 0, stream, image, guidance, out);
}

// Round 3
// 75.463 us; speedup vs baseline: 1.1504x; 1.0207x over previous
//
#include <hip/hip_runtime.h>

#define RADIUS 5
#define KSIZE  11
#define TXN    16                   // threads in x
#define TYN    16                   // threads in y
#define TILEX  32                   // output px per block in x (2 per thread)
#define TILEY  16
#define HX     (TILEX + 2*RADIUS)   // 42
#define HY     (TILEY + 2*RADIUS)   // 26
#define HPITCH 21                   // half-columns per row (42/2), odd
#define H      256
#define W      256

// -0.5*log2(e)*sigma_inv, groups: ch0-1 (10.0), ch2-4 (0.02), ch5-7 (0.1)
#define COEF_A (-0.072134752f)
#define COEF_B (-36.06737602f)
#define COEF_C (-7.213475204f)

__device__ __forceinline__ float wcalc(const float4 a, const float4 g,
                                       const float4 cA, const float4 cB) {
    const float d0 = a.x - cA.x, d1 = a.y - cA.y;
    const float d2 = a.z - cA.z, d3 = a.w - cA.w;
    const float d4 = g.x - cB.x, d5 = g.y - cB.y;
    const float d6 = g.z - cB.z, d7 = g.w - cB.w;
    const float sA = d0 * d0 + d1 * d1;
    const float sB = d2 * d2 + d3 * d3 + d4 * d4;
    const float sC = d5 * d5 + d6 * d6 + d7 * d7;
    return __builtin_amdgcn_exp2f(COEF_A * sA + COEF_B * sB + COEF_C * sC);
}

__global__ __launch_bounds__(256, 1) void jbf_kernel(
    const float* __restrict__ image,     // (B,3,H,W)
    const float* __restrict__ guidance,  // (B,8,H,W)
    float* __restrict__ out)             // (B,3,H,W)
{
    // even/odd column split: for fixed (dy,k) every lane reads ONE sub-array
    // at 16 B lane stride -> conflict-free ds_read_b128
    __shared__ float4 g0e[HY * HPITCH], g0o[HY * HPITCH];  // guidance ch0-3
    __shared__ float4 g1e[HY * HPITCH], g1o[HY * HPITCH];  // guidance ch4-7
    __shared__ float4 ime[HY * HPITCH], imo[HY * HPITCH];  // image ch0-2

    const int b       = blockIdx.z;
    const int tile_x0 = blockIdx.x * TILEX;
    const int tile_y0 = blockIdx.y * TILEY;
    const int tid     = threadIdx.y * TXN + threadIdx.x;

    const float* gbase = guidance + (size_t)b * 8 * H * W;
    const float* ibase = image    + (size_t)b * 3 * H * W;

    // ---- stage 42x26 halo (reflect) into even/odd interleaved LDS ----
    for (int idx = tid; idx < HX * HY; idx += TXN * TYN) {
        const int ly = idx / HX;
        const int lx = idx - ly * HX;
        int gy = tile_y0 - RADIUS + ly;
        int gx = tile_x0 - RADIUS + lx;
        gy = (gy < 0) ? -gy : ((gy >= H) ? 2 * (H - 1) - gy : gy);
        gx = (gx < 0) ? -gx : ((gx >= W) ? 2 * (W - 1) - gx : gx);
        const int off = gy * W + gx;
        const int l   = ly * HPITCH + (lx >> 1);
        const float4 v0 = make_float4(gbase[0*H*W+off], gbase[1*H*W+off],
                                      gbase[2*H*W+off], gbase[3*H*W+off]);
        const float4 v1 = make_float4(gbase[4*H*W+off], gbase[5*H*W+off],
                                      gbase[6*H*W+off], gbase[7*H*W+off]);
        const float4 vi = make_float4(ibase[0*H*W+off], ibase[1*H*W+off],
                                      ibase[2*H*W+off], 0.f);
        if (lx & 1) { g0o[l] = v0; g1o[l] = v1; imo[l] = vi; }
        else        { g0e[l] = v0; g1e[l] = v1; ime[l] = vi; }
    }
    __syncthreads();

    const int tx = threadIdx.x;
    const int ty = threadIdx.y;

    // centers: px0 local col = 2tx+5 (odd, half-idx tx+2); px1 = 2tx+6 (even, tx+3)
    const int crow = (ty + RADIUS) * HPITCH;
    const float4 c0A = g0o[crow + tx + 2], c0B = g1o[crow + tx + 2];
    const float4 c1A = g0e[crow + tx + 3], c1B = g1e[crow + tx + 3];

    float a00 = 0.f, a01 = 0.f, a02 = 0.f, sw0 = 0.f;
    float a10 = 0.f, a11 = 0.f, a12 = 0.f, sw1 = 0.f;

    for (int dy = 0; dy < KSIZE; ++dy) {
        const int rb = (ty + dy) * HPITCH + tx;
        #pragma unroll
        for (int k = 0; k <= 5; ++k) {
            const float4 Eg0 = g0e[rb + k], Eg1 = g1e[rb + k], Eim = ime[rb + k];
            const float4 Og0 = g0o[rb + k], Og1 = g1o[rb + k], Oim = imo[rb + k];

            {   // px0, dx=2k (even col)
                const float w = wcalc(Eg0, Eg1, c0A, c0B);
                sw0 += w; a00 += w * Eim.x; a01 += w * Eim.y; a02 += w * Eim.z;
            }
            if (k <= 4) {  // px0, dx=2k+1 (odd col)
                const float w = wcalc(Og0, Og1, c0A, c0B);
                sw0 += w; a00 += w * Oim.x; a01 += w * Oim.y; a02 += w * Oim.z;
            }
            {   // px1, dx=2k (odd col)
                const float w = wcalc(Og0, Og1, c1A, c1B);
                sw1 += w; a10 += w * Oim.x; a11 += w * Oim.y; a12 += w * Oim.z;
            }
            if (k >= 1) {  // px1, dx=2k-1 (even col)
                const float w = wcalc(Eg0, Eg1, c1A, c1B);
                sw1 += w; a10 += w * Eim.x; a11 += w * Eim.y; a12 += w * Eim.z;
            }
        }
    }

    // sum_w >= 1 (center weight = 1); reference clip(1e-10) is a no-op
    const float inv0 = 1.0f / sw0;
    const float inv1 = 1.0f / sw1;
    const size_t o = (size_t)b * 3 * H * W + (size_t)(tile_y0 + ty) * W
                   + (size_t)(tile_x0 + 2 * tx);
    float2* __restrict__ o2 = (float2*)(out + o);
    o2[0]             = make_float2(a00 * inv0, a10 * inv1);
    o2[(H*W) / 2]     = make_float2(a01 * inv0, a11 * inv1);
    o2[(2*H*W) / 2]   = make_float2(a02 * inv0, a12 * inv1);
}

extern "C" void kernel_launch(void* const* d_in, const int* in_sizes, int n_in,
                              void* d_out, int out_size, void* d_ws, size_t ws_size,
                              hipStream_t stream) {
    const float* image    = (const float*)d_in[0];
    const float* guidance = (const float*)d_in[1];
    float* out            = (float*)d_out;

    const int B = in_sizes[0] / (3 * H * W);   // = 2
    dim3 grid(W / TILEX, H / TILEY, B);        // 8 x 16 x 2 = 256 blocks
    dim3 block(TXN, TYN);
    hipLaunchKernelGGL(jbf_kernel, grid, block, 0, stream, image, guidance, out);
}

// Round 4
// 73.765 us; speedup vs baseline: 1.1769x; 1.0230x over previous
//
#include <hip/hip_runtime.h>

#define RADIUS 5
#define KSIZE  11
#define TILEX  32                   // output px per block in x (2 per px-pair thread)
#define TILEY  16
#define HX     (TILEX + 2*RADIUS)   // 42
#define HY     (TILEY + 2*RADIUS)   // 26
#define HPITCH 21                   // half-columns per row (42/2), odd
#define H      256
#define W      256

// -0.5*log2(e)*sigma_inv, groups: ch0-1 (10.0), ch2-4 (0.02), ch5-7 (0.1)
#define COEF_A (-0.072134752f)
#define COEF_B (-36.06737602f)
#define COEF_C (-7.213475204f)

__device__ __forceinline__ float wcalc(const float4 a, const float4 g,
                                       const float4 cA, const float4 cB) {
    const float d0 = a.x - cA.x, d1 = a.y - cA.y;
    const float d2 = a.z - cA.z, d3 = a.w - cA.w;
    const float d4 = g.x - cB.x, d5 = g.y - cB.y;
    const float d6 = g.z - cB.z, d7 = g.w - cB.w;
    const float sA = d0 * d0 + d1 * d1;
    const float sB = d2 * d2 + d3 * d3 + d4 * d4;
    const float sC = d5 * d5 + d6 * d6 + d7 * d7;
    return __builtin_amdgcn_exp2f(COEF_A * sA + COEF_B * sB + COEF_C * sC);
}

// block (2,16,16): threadIdx.x = dy-half (lane bit 0 -> shfl_xor combine),
// threadIdx.y = px-pair x, threadIdx.z = px y. 512 thr = 8 waves -> 2 waves/SIMD.
__global__ __launch_bounds__(512, 2) void jbf_kernel(
    const float* __restrict__ image,     // (B,3,H,W)
    const float* __restrict__ guidance,  // (B,8,H,W)
    float* __restrict__ out)             // (B,3,H,W)
{
    // even/odd column split: for fixed (dy,k) every lane reads ONE sub-array
    // at 16 B lane stride -> conflict-free ds_read_b128
    __shared__ float4 g0e[HY * HPITCH], g0o[HY * HPITCH];  // guidance ch0-3
    __shared__ float4 g1e[HY * HPITCH], g1o[HY * HPITCH];  // guidance ch4-7
    __shared__ float4 ime[HY * HPITCH], imo[HY * HPITCH];  // image ch0-2

    const int b       = blockIdx.z;
    const int tile_x0 = blockIdx.x * TILEX;
    const int tile_y0 = blockIdx.y * TILEY;
    const int half    = threadIdx.x;        // 0: even dy rows, 1: odd dy rows
    const int txp     = threadIdx.y;        // px-pair index in x
    const int typ     = threadIdx.z;        // px y within tile
    const int tid     = (typ * 16 + txp) * 2 + half;

    const float* gbase = guidance + (size_t)b * 8 * H * W;
    const float* ibase = image    + (size_t)b * 3 * H * W;

    // ---- stage 42x26 halo (reflect) into even/odd interleaved LDS ----
    for (int idx = tid; idx < HX * HY; idx += 512) {
        const int ly = idx / HX;
        const int lx = idx - ly * HX;
        int gy = tile_y0 - RADIUS + ly;
        int gx = tile_x0 - RADIUS + lx;
        gy = (gy < 0) ? -gy : ((gy >= H) ? 2 * (H - 1) - gy : gy);
        gx = (gx < 0) ? -gx : ((gx >= W) ? 2 * (W - 1) - gx : gx);
        const int off = gy * W + gx;
        const int l   = ly * HPITCH + (lx >> 1);
        const float4 v0 = make_float4(gbase[0*H*W+off], gbase[1*H*W+off],
                                      gbase[2*H*W+off], gbase[3*H*W+off]);
        const float4 v1 = make_float4(gbase[4*H*W+off], gbase[5*H*W+off],
                                      gbase[6*H*W+off], gbase[7*H*W+off]);
        const float4 vi = make_float4(ibase[0*H*W+off], ibase[1*H*W+off],
                                      ibase[2*H*W+off], 0.f);
        if (lx & 1) { g0o[l] = v0; g1o[l] = v1; imo[l] = vi; }
        else        { g0e[l] = v0; g1e[l] = v1; ime[l] = vi; }
    }
    __syncthreads();

    // centers: px0 local col = 2txp+5 (odd, half-idx txp+2); px1 = 2txp+6 (even, txp+3)
    const int crow = (typ + RADIUS) * HPITCH;
    const float4 c0A = g0o[crow + txp + 2], c0B = g1o[crow + txp + 2];
    const float4 c1A = g0e[crow + txp + 3], c1B = g1e[crow + txp + 3];

    float a00 = 0.f, a01 = 0.f, a02 = 0.f, sw0 = 0.f;
    float a10 = 0.f, a11 = 0.f, a12 = 0.f, sw1 = 0.f;

    // half 0 does dy = 0,2,4,6,8,10; half 1 does dy = 1,3,5,7,9
    for (int i = 0; i < 6; ++i) {
        const int dy = 2 * i + half;
        if (dy < KSIZE) {
            const int rb = (typ + dy) * HPITCH + txp;
            #pragma unroll
            for (int k = 0; k <= 5; ++k) {
                const float4 Eg0 = g0e[rb + k], Eg1 = g1e[rb + k], Eim = ime[rb + k];
                const float4 Og0 = g0o[rb + k], Og1 = g1o[rb + k], Oim = imo[rb + k];

                {   // px0, dx=2k (even col)
                    const float w = wcalc(Eg0, Eg1, c0A, c0B);
                    sw0 += w; a00 += w * Eim.x; a01 += w * Eim.y; a02 += w * Eim.z;
                }
                if (k <= 4) {  // px0, dx=2k+1 (odd col)
                    const float w = wcalc(Og0, Og1, c0A, c0B);
                    sw0 += w; a00 += w * Oim.x; a01 += w * Oim.y; a02 += w * Oim.z;
                }
                {   // px1, dx=2k (odd col)
                    const float w = wcalc(Og0, Og1, c1A, c1B);
                    sw1 += w; a10 += w * Oim.x; a11 += w * Oim.y; a12 += w * Oim.z;
                }
                if (k >= 1) {  // px1, dx=2k-1 (even col)
                    const float w = wcalc(Eg0, Eg1, c1A, c1B);
                    sw1 += w; a10 += w * Eim.x; a11 += w * Eim.y; a12 += w * Eim.z;
                }
            }
        }
    }

    // combine dy-half partials: partner is lane^1 (half is lane bit 0)
    sw0 += __shfl_xor(sw0, 1);
    a00 += __shfl_xor(a00, 1);
    a01 += __shfl_xor(a01, 1);
    a02 += __shfl_xor(a02, 1);
    sw1 += __shfl_xor(sw1, 1);
    a10 += __shfl_xor(a10, 1);
    a11 += __shfl_xor(a11, 1);
    a12 += __shfl_xor(a12, 1);

    if (half == 0) {
        // sum_w >= 1 (center weight = 1); reference clip(1e-10) is a no-op
        const float inv0 = 1.0f / sw0;
        const float inv1 = 1.0f / sw1;
        const size_t o = (size_t)b * 3 * H * W + (size_t)(tile_y0 + typ) * W
                       + (size_t)(tile_x0 + 2 * txp);
        float2* __restrict__ o2 = (float2*)(out + o);
        o2[0]           = make_float2(a00 * inv0, a10 * inv1);
        o2[(H*W) / 2]   = make_float2(a01 * inv0, a11 * inv1);
        o2[(2*H*W) / 2] = make_float2(a02 * inv0, a12 * inv1);
    }
}

extern "C" void kernel_launch(void* const* d_in, const int* in_sizes, int n_in,
                              void* d_out, int out_size, void* d_ws, size_t ws_size,
                              hipStream_t stream) {
    const float* image    = (const float*)d_in[0];
    const float* guidance = (const float*)d_in[1];
    float* out            = (float*)d_out;

    const int B = in_sizes[0] / (3 * H * W);   // = 2
    dim3 grid(W / TILEX, H / TILEY, B);        // 8 x 16 x 2 = 256 blocks
    dim3 block(2, 16, 16);                     // 512 threads = 8 waves
    hipLaunchKernelGGL(jbf_kernel, grid, block, 0, stream, image, guidance, out);
}

// Round 5
// 73.310 us; speedup vs baseline: 1.1842x; 1.0062x over previous
//
#include <hip/hip_runtime.h>

#define RADIUS 5
#define KSIZE  11
#define TILEX  32                   // output px per block in x (2 per px-pair)
#define TILEY  16
#define HX     (TILEX + 2*RADIUS)   // 42
#define HY     (TILEY + 2*RADIUS)   // 26
#define HPITCH 21                   // half-columns per row (42/2), odd
#define H      256
#define W      256

// -0.5*log2(e)*sigma_inv, groups: ch0-1 (10.0), ch2-4 (0.02), ch5-7 (0.1)
#define COEF_A (-0.072134752f)
#define COEF_B (-36.06737602f)
#define COEF_C (-7.213475204f)

__device__ __forceinline__ float wcalc(const float4 a, const float4 g,
                                       const float4 cA, const float4 cB) {
    const float d0 = a.x - cA.x, d1 = a.y - cA.y;
    const float d2 = a.z - cA.z, d3 = a.w - cA.w;
    const float d4 = g.x - cB.x, d5 = g.y - cB.y;
    const float d6 = g.z - cB.z, d7 = g.w - cB.w;
    const float sA = d0 * d0 + d1 * d1;
    const float sB = d2 * d2 + d3 * d3 + d4 * d4;
    const float sC = d5 * d5 + d6 * d6 + d7 * d7;
    return __builtin_amdgcn_exp2f(COEF_A * sA + COEF_B * sB + COEF_C * sC);
}

// block (4,16,16): threadIdx.x = dy-quarter (lane bits 0-1 -> shfl_xor combine),
// threadIdx.y = px-pair x, threadIdx.z = px y. 1024 thr = 16 waves -> 4 waves/SIMD.
__global__ __launch_bounds__(1024, 4) void jbf_kernel(
    const float* __restrict__ image,     // (B,3,H,W)
    const float* __restrict__ guidance,  // (B,8,H,W)
    float* __restrict__ out)             // (B,3,H,W)
{
    // even/odd column split keeps lane stride at 16 B -> conflict-free b128
    __shared__ float4 g0e[HY * HPITCH], g0o[HY * HPITCH];  // guidance ch0-3
    __shared__ float4 g1e[HY * HPITCH], g1o[HY * HPITCH];  // guidance ch4-7
    __shared__ float4 ime[HY * HPITCH], imo[HY * HPITCH];  // image ch0-2

    const int b       = blockIdx.z;
    const int tile_x0 = blockIdx.x * TILEX;
    const int tile_y0 = blockIdx.y * TILEY;
    const int h       = threadIdx.x;        // dy-quarter 0..3
    const int txp     = threadIdx.y;        // px-pair index in x
    const int typ     = threadIdx.z;        // px y within tile
    const int tid     = (typ * 16 + txp) * 4 + h;

    const float* gbase = guidance + (size_t)b * 8 * H * W;
    const float* ibase = image    + (size_t)b * 3 * H * W;

    // ---- stage 42x26 halo (reflect) into even/odd interleaved LDS ----
    for (int idx = tid; idx < HX * HY; idx += 1024) {
        const int ly = idx / HX;
        const int lx = idx - ly * HX;
        int gy = tile_y0 - RADIUS + ly;
        int gx = tile_x0 - RADIUS + lx;
        gy = (gy < 0) ? -gy : ((gy >= H) ? 2 * (H - 1) - gy : gy);
        gx = (gx < 0) ? -gx : ((gx >= W) ? 2 * (W - 1) - gx : gx);
        const int off = gy * W + gx;
        const int l   = ly * HPITCH + (lx >> 1);
        const float4 v0 = make_float4(gbase[0*H*W+off], gbase[1*H*W+off],
                                      gbase[2*H*W+off], gbase[3*H*W+off]);
        const float4 v1 = make_float4(gbase[4*H*W+off], gbase[5*H*W+off],
                                      gbase[6*H*W+off], gbase[7*H*W+off]);
        const float4 vi = make_float4(ibase[0*H*W+off], ibase[1*H*W+off],
                                      ibase[2*H*W+off], 0.f);
        if (lx & 1) { g0o[l] = v0; g1o[l] = v1; imo[l] = vi; }
        else        { g0e[l] = v0; g1e[l] = v1; ime[l] = vi; }
    }
    __syncthreads();

    // centers: px0 local col = 2txp+5 (odd, half-idx txp+2); px1 = 2txp+6 (even, txp+3)
    const int crow = (typ + RADIUS) * HPITCH;
    const float4 c0A = g0o[crow + txp + 2], c0B = g1o[crow + txp + 2];
    const float4 c1A = g0e[crow + txp + 3], c1B = g1e[crow + txp + 3];

    float a00 = 0.f, a01 = 0.f, a02 = 0.f, sw0 = 0.f;
    float a10 = 0.f, a11 = 0.f, a12 = 0.f, sw1 = 0.f;

    // quarter h does dy = h, h+4, h+8 (h=3: dy=3,7 only)
    #pragma unroll
    for (int i = 0; i < 3; ++i) {
        const int dy = 4 * i + h;
        if (dy < KSIZE) {
            const int rb = (typ + dy) * HPITCH + txp;
            #pragma unroll
            for (int k = 0; k <= 5; ++k) {
                const float4 Eg0 = g0e[rb + k], Eg1 = g1e[rb + k], Eim = ime[rb + k];
                const float4 Og0 = g0o[rb + k], Og1 = g1o[rb + k], Oim = imo[rb + k];

                {   // px0, dx=2k (even col)
                    const float w = wcalc(Eg0, Eg1, c0A, c0B);
                    sw0 += w; a00 += w * Eim.x; a01 += w * Eim.y; a02 += w * Eim.z;
                }
                if (k <= 4) {  // px0, dx=2k+1 (odd col)
                    const float w = wcalc(Og0, Og1, c0A, c0B);
                    sw0 += w; a00 += w * Oim.x; a01 += w * Oim.y; a02 += w * Oim.z;
                }
                {   // px1, dx=2k (odd col)
                    const float w = wcalc(Og0, Og1, c1A, c1B);
                    sw1 += w; a10 += w * Oim.x; a11 += w * Oim.y; a12 += w * Oim.z;
                }
                if (k >= 1) {  // px1, dx=2k-1 (even col)
                    const float w = wcalc(Eg0, Eg1, c1A, c1B);
                    sw1 += w; a10 += w * Eim.x; a11 += w * Eim.y; a12 += w * Eim.z;
                }
            }
        }
    }

    // combine dy-quarter partials: butterfly over lane bits 0-1
    sw0 += __shfl_xor(sw0, 1);  sw0 += __shfl_xor(sw0, 2);
    a00 += __shfl_xor(a00, 1);  a00 += __shfl_xor(a00, 2);
    a01 += __shfl_xor(a01, 1);  a01 += __shfl_xor(a01, 2);
    a02 += __shfl_xor(a02, 1);  a02 += __shfl_xor(a02, 2);
    sw1 += __shfl_xor(sw1, 1);  sw1 += __shfl_xor(sw1, 2);
    a10 += __shfl_xor(a10, 1);  a10 += __shfl_xor(a10, 2);
    a11 += __shfl_xor(a11, 1);  a11 += __shfl_xor(a11, 2);
    a12 += __shfl_xor(a12, 1);  a12 += __shfl_xor(a12, 2);

    if (h == 0) {
        // sum_w >= 1 (center weight = 1); reference clip(1e-10) is a no-op
        const float inv0 = 1.0f / sw0;
        const float inv1 = 1.0f / sw1;
        const size_t o = (size_t)b * 3 * H * W + (size_t)(tile_y0 + typ) * W
                       + (size_t)(tile_x0 + 2 * txp);
        float2* __restrict__ o2 = (float2*)(out + o);
        o2[0]           = make_float2(a00 * inv0, a10 * inv1);
        o2[(H*W) / 2]   = make_float2(a01 * inv0, a11 * inv1);
        o2[(2*H*W) / 2] = make_float2(a02 * inv0, a12 * inv1);
    }
}

extern "C" void kernel_launch(void* const* d_in, const int* in_sizes, int n_in,
                              void* d_out, int out_size, void* d_ws, size_t ws_size,
                              hipStream_t stream) {
    const float* image    = (const float*)d_in[0];
    const float* guidance = (const float*)d_in[1];
    float* out            = (float*)d_out;

    const int B = in_sizes[0] / (3 * H * W);   // = 2
    dim3 grid(W / TILEX, H / TILEY, B);        // 8 x 16 x 2 = 256 blocks
    dim3 block(4, 16, 16);                     // 1024 threads = 16 waves
    hipLaunchKernelGGL(jbf_kernel, grid, block, 0, stream, image, guidance, out);
}

// Round 6
// 72.467 us; speedup vs baseline: 1.1979x; 1.0116x over previous
//
#include <hip/hip_runtime.h>

#define RADIUS 5
#define KSIZE  11
#define TILEX  32                   // output px per block in x (2 per px-pair)
#define TILEY  16
#define HX     (TILEX + 2*RADIUS)   // 42
#define HY     (TILEY + 2*RADIUS)   // 26
#define HPITCH 21                   // half-columns per row (42/2), odd
#define H      256
#define W      256

// -0.5*log2(e)*sigma_inv, groups: ch0-1 (10.0), ch2-4 (0.02), ch5-7 (0.1)
#define COEF_A (-0.072134752f)
#define COEF_B (-36.06737602f)
#define COEF_C (-7.213475204f)

__device__ __forceinline__ float wcalc(const float4 a, const float4 g,
                                       const float4 cA, const float4 cB) {
    const float d0 = a.x - cA.x, d1 = a.y - cA.y;
    const float d2 = a.z - cA.z, d3 = a.w - cA.w;
    const float d4 = g.x - cB.x, d5 = g.y - cB.y;
    const float d6 = g.z - cB.z, d7 = g.w - cB.w;
    const float sA = d0 * d0 + d1 * d1;
    const float sB = d2 * d2 + d3 * d3 + d4 * d4;
    const float sC = d5 * d5 + d6 * d6 + d7 * d7;
    return __builtin_amdgcn_exp2f(COEF_A * sA + COEF_B * sB + COEF_C * sC);
}

// block (16,4,16): threadIdx.x = px-pair (lane bits 0-3 -> quarter-wave reads one
// contiguous row segment, conflict-free b128), threadIdx.y = dy-quarter (lane
// bits 4-5 -> shfl_xor(16/32) combine), threadIdx.z = px y (= wave index).
__global__ __launch_bounds__(1024, 4) void jbf_kernel(
    const float* __restrict__ image,     // (B,3,H,W)
    const float* __restrict__ guidance,  // (B,8,H,W)
    float* __restrict__ out)             // (B,3,H,W)
{
    // even/odd column split keeps lane stride at 16 B -> contiguous b128
    __shared__ float4 g0e[HY * HPITCH], g0o[HY * HPITCH];  // guidance ch0-3
    __shared__ float4 g1e[HY * HPITCH], g1o[HY * HPITCH];  // guidance ch4-7
    __shared__ float4 ime[HY * HPITCH], imo[HY * HPITCH];  // image ch0-2

    const int b       = blockIdx.z;
    const int tile_x0 = blockIdx.x * TILEX;
    const int tile_y0 = blockIdx.y * TILEY;
    const int txp     = threadIdx.x;        // px-pair index in x (lane bits 0-3)
    const int h       = threadIdx.y;        // dy-quarter 0..3 (lane bits 4-5)
    const int typ     = threadIdx.z;        // px y within tile (wave index)
    const int tid     = (typ * 4 + h) * 16 + txp;

    const float* gbase = guidance + (size_t)b * 8 * H * W;
    const float* ibase = image    + (size_t)b * 3 * H * W;

    // ---- stage 42x26 halo (reflect) into even/odd interleaved LDS ----
    for (int idx = tid; idx < HX * HY; idx += 1024) {
        const int ly = idx / HX;
        const int lx = idx - ly * HX;
        int gy = tile_y0 - RADIUS + ly;
        int gx = tile_x0 - RADIUS + lx;
        gy = (gy < 0) ? -gy : ((gy >= H) ? 2 * (H - 1) - gy : gy);
        gx = (gx < 0) ? -gx : ((gx >= W) ? 2 * (W - 1) - gx : gx);
        const int off = gy * W + gx;
        const int l   = ly * HPITCH + (lx >> 1);
        const float4 v0 = make_float4(gbase[0*H*W+off], gbase[1*H*W+off],
                                      gbase[2*H*W+off], gbase[3*H*W+off]);
        const float4 v1 = make_float4(gbase[4*H*W+off], gbase[5*H*W+off],
                                      gbase[6*H*W+off], gbase[7*H*W+off]);
        const float4 vi = make_float4(ibase[0*H*W+off], ibase[1*H*W+off],
                                      ibase[2*H*W+off], 0.f);
        if (lx & 1) { g0o[l] = v0; g1o[l] = v1; imo[l] = vi; }
        else        { g0e[l] = v0; g1e[l] = v1; ime[l] = vi; }
    }
    __syncthreads();

    // centers: px0 local col = 2txp+5 (odd, half-idx txp+2); px1 = 2txp+6 (even, txp+3)
    const int crow = (typ + RADIUS) * HPITCH;
    const float4 c0A = g0o[crow + txp + 2], c0B = g1o[crow + txp + 2];
    const float4 c1A = g0e[crow + txp + 3], c1B = g1e[crow + txp + 3];

    float a00 = 0.f, a01 = 0.f, a02 = 0.f, sw0 = 0.f;
    float a10 = 0.f, a11 = 0.f, a12 = 0.f, sw1 = 0.f;

    // quarter h does dy = h, h+4, h+8 (h=3: dy=3,7 only)
    #pragma unroll
    for (int i = 0; i < 3; ++i) {
        const int dy = 4 * i + h;
        if (dy < KSIZE) {
            const int rb = (typ + dy) * HPITCH + txp;
            #pragma unroll
            for (int k = 0; k <= 5; ++k) {
                const float4 Eg0 = g0e[rb + k], Eg1 = g1e[rb + k], Eim = ime[rb + k];
                const float4 Og0 = g0o[rb + k], Og1 = g1o[rb + k], Oim = imo[rb + k];

                {   // px0, dx=2k (even col)
                    const float w = wcalc(Eg0, Eg1, c0A, c0B);
                    sw0 += w; a00 += w * Eim.x; a01 += w * Eim.y; a02 += w * Eim.z;
                }
                if (k <= 4) {  // px0, dx=2k+1 (odd col)
                    const float w = wcalc(Og0, Og1, c0A, c0B);
                    sw0 += w; a00 += w * Oim.x; a01 += w * Oim.y; a02 += w * Oim.z;
                }
                {   // px1, dx=2k (odd col)
                    const float w = wcalc(Og0, Og1, c1A, c1B);
                    sw1 += w; a10 += w * Oim.x; a11 += w * Oim.y; a12 += w * Oim.z;
                }
                if (k >= 1) {  // px1, dx=2k-1 (even col)
                    const float w = wcalc(Eg0, Eg1, c1A, c1B);
                    sw1 += w; a10 += w * Eim.x; a11 += w * Eim.y; a12 += w * Eim.z;
                }
            }
        }
    }

    // combine dy-quarter partials: butterfly over lane bits 4-5 (h)
    sw0 += __shfl_xor(sw0, 16);  sw0 += __shfl_xor(sw0, 32);
    a00 += __shfl_xor(a00, 16);  a00 += __shfl_xor(a00, 32);
    a01 += __shfl_xor(a01, 16);  a01 += __shfl_xor(a01, 32);
    a02 += __shfl_xor(a02, 16);  a02 += __shfl_xor(a02, 32);
    sw1 += __shfl_xor(sw1, 16);  sw1 += __shfl_xor(sw1, 32);
    a10 += __shfl_xor(a10, 16);  a10 += __shfl_xor(a10, 32);
    a11 += __shfl_xor(a11, 16);  a11 += __shfl_xor(a11, 32);
    a12 += __shfl_xor(a12, 16);  a12 += __shfl_xor(a12, 32);

    if (h == 0) {
        // sum_w >= 1 (center weight = 1); reference clip(1e-10) is a no-op
        const float inv0 = 1.0f / sw0;
        const float inv1 = 1.0f / sw1;
        const size_t o = (size_t)b * 3 * H * W + (size_t)(tile_y0 + typ) * W
                       + (size_t)(tile_x0 + 2 * txp);
        float2* __restrict__ o2 = (float2*)(out + o);
        o2[0]           = make_float2(a00 * inv0, a10 * inv1);
        o2[(H*W) / 2]   = make_float2(a01 * inv0, a11 * inv1);
        o2[(2*H*W) / 2] = make_float2(a02 * inv0, a12 * inv1);
    }
}

extern "C" void kernel_launch(void* const* d_in, const int* in_sizes, int n_in,
                              void* d_out, int out_size, void* d_ws, size_t ws_size,
                              hipStream_t stream) {
    const float* image    = (const float*)d_in[0];
    const float* guidance = (const float*)d_in[1];
    float* out            = (float*)d_out;

    const int B = in_sizes[0] / (3 * H * W);   // = 2
    dim3 grid(W / TILEX, H / TILEY, B);        // 8 x 16 x 2 = 256 blocks
    dim3 block(16, 4, 16);                     // 1024 threads = 16 waves
    hipLaunchKernelGGL(jbf_kernel, grid, block, 0, stream, image, guidance, out);
}